// Round 1
// baseline (381.829 us; speedup 1.0000x reference)
//
#include <hip/hip_runtime.h>
#include <hip/hip_bf16.h>
#include <cstdint>
#include <cstddef>

// Problem constants
#define NTOK 49
#define DIM 384
#define HEADS 12
#define HD 32
#define NWIN 64
#define BATCH 2048
#define MROWS (BATCH * NTOK)   // 100352 = 784 * 128

typedef unsigned short u16;
typedef __bf16 bf16x8 __attribute__((ext_vector_type(8)));
typedef unsigned short u16x8 __attribute__((ext_vector_type(8)));
typedef float f32x4 __attribute__((ext_vector_type(4)));

__device__ __forceinline__ u16 f2b(float f) {
  union { float f; unsigned u; } v; v.f = f;
  unsigned r = v.u + 0x7fffu + ((v.u >> 16) & 1u);   // RNE bf16
  return (u16)(r >> 16);
}

__device__ __forceinline__ bf16x8 ld_bf8(const u16* p) {
  u16x8 u = *(const u16x8*)p;
  return __builtin_bit_cast(bf16x8, u);
}

__device__ __forceinline__ void gload_lds16(const void* g, void* l) {
  __builtin_amdgcn_global_load_lds(
      (const __attribute__((address_space(1))) unsigned*)g,
      (__attribute__((address_space(3))) unsigned*)l, 16, 0, 0);
}

// ---------------- cast fp32 -> bf16 (vectorized) ----------------
__global__ __launch_bounds__(256) void k_cast(const float* __restrict__ in,
                                              u16* __restrict__ out, int n4) {
  int i = blockIdx.x * 256 + threadIdx.x;
  if (i < n4) {
    float4 v = ((const float4*)in)[i];
    ushort4 o;
    o.x = f2b(v.x); o.y = f2b(v.y); o.z = f2b(v.z); o.w = f2b(v.w);
    ((ushort4*)out)[i] = o;
  }
}

// -------- fused rel-pos-bias + mask table, pre-swizzled to MFMA C-layout ----
// layout: [(h*64+w)][ (mi*4+ni) ][ lane ][ r ]  (4096 floats per (h,w))
// value = bias_table[rel_idx[row][col]*12+h] + mask[w][row][col], or -1e30 pad
__global__ __launch_bounds__(256) void k_rpbm(const float* __restrict__ bias_table,
                                              const float* __restrict__ mask,
                                              const int* __restrict__ rel_idx,
                                              float* __restrict__ out) {
  int idx = blockIdx.x * 256 + threadIdx.x;   // grid = 12*64*4096/256 = 12288
  int r  = idx & 3;
  int l  = (idx >> 2) & 63;
  int ni = (idx >> 8) & 3;
  int mi = (idx >> 10) & 3;
  int w  = (idx >> 12) & 63;
  int h  = idx >> 18;
  int row = mi * 16 + (l >> 4) * 4 + r;
  int col = ni * 16 + (l & 15);
  float v = -1e30f;
  if (row < NTOK && col < NTOK)
    v = bias_table[rel_idx[row * NTOK + col] * HEADS + h] +
        mask[(w * NTOK + row) * NTOK + col];
  out[idx] = v;
}

// ---------------- NT GEMM: C[m,n] = sum_k A[m,k]*B[n,k] + bias[n] ----------
// A [M,K] bf16 row-major, B [N,K] bf16 row-major, K%32==0, M%128==0, N%128==0
template <int OUT_BF16>
__global__ __launch_bounds__(256) void k_gemm(const u16* __restrict__ A,
                                              const u16* __restrict__ B,
                                              const float* __restrict__ bias,
                                              void* __restrict__ Cv,
                                              int K, int N, int ntn, int grid_div8) {
  __shared__ u16 As[128 * 32];
  __shared__ u16 Bs[128 * 32];
  int bid = blockIdx.x;
  int tile = (bid & 7) * grid_div8 + (bid >> 3);   // XCD-contiguous mapping
  int mt = tile / ntn, nt = tile % ntn;
  long m0 = (long)mt * 128;
  int n0 = nt * 128;
  int tid = threadIdx.x;
  int lane = tid & 63, wid = tid >> 6;
  int wr = (wid >> 1) * 64, wc = (wid & 1) * 64;
  int c = lane & 15, g = lane >> 4;

  // staging: thread covers row (wid*16+lane/4), 8 elems at col (lane&3)*8
  int srow = wid * 16 + (lane >> 2);
  int scol = (lane & 3) * 8;
  const u16* gA = A + (m0 + srow) * (long)K + scol;
  const u16* gB = B + (long)(n0 + srow) * K + scol;
  u16* lA = &As[srow * 32 + scol];
  u16* lB = &Bs[srow * 32 + scol];

  f32x4 acc[4][4] = {};
  for (int kt = 0; kt < K; kt += 32) {
    __syncthreads();
    gload_lds16(gA + kt, lA);
    gload_lds16(gA + kt + 64L * K, lA + 64 * 32);
    gload_lds16(gB + kt, lB);
    gload_lds16(gB + kt + 64L * K, lB + 64 * 32);
    __syncthreads();   // compiler emits vmcnt(0) drain before barrier
    bf16x8 af[4], bf_[4];
#pragma unroll
    for (int i = 0; i < 4; ++i) {
      af[i]  = ld_bf8(&As[(wr + i * 16 + c) * 32 + g * 8]);
      bf_[i] = ld_bf8(&Bs[(wc + i * 16 + c) * 32 + g * 8]);
    }
#pragma unroll
    for (int mi = 0; mi < 4; ++mi)
#pragma unroll
      for (int ni = 0; ni < 4; ++ni)
        acc[mi][ni] = __builtin_amdgcn_mfma_f32_16x16x32_bf16(
            af[mi], bf_[ni], acc[mi][ni], 0, 0, 0);
  }

  // epilogue: D row=(lane>>4)*4+r, col=lane&15 within each 16x16 fragment
#pragma unroll
  for (int mi = 0; mi < 4; ++mi)
#pragma unroll
    for (int ni = 0; ni < 4; ++ni) {
      int colg = n0 + wc + ni * 16 + c;
      float bv = bias[colg];
#pragma unroll
      for (int r = 0; r < 4; ++r) {
        long rowg = m0 + wr + mi * 16 + g * 4 + r;
        float val = acc[mi][ni][r] + bv;
        if (OUT_BF16)
          ((u16*)Cv)[rowg * N + colg] = f2b(val);
        else
          ((float*)Cv)[rowg * N + colg] = val;
      }
    }
}

// ---------------- fused window attention: one wave per (b, h) ----------------
__global__ __launch_bounds__(256) void k_attn(const u16* __restrict__ qkv,
                                              const float* __restrict__ rpbm,
                                              u16* __restrict__ attnout) {
  __shared__ u16 P_lds[4][64 * 64];
  __shared__ u16 vT_lds[4][32 * 64];
  int lane = threadIdx.x & 63, wid = threadIdx.x >> 6;
  int task = blockIdx.x * 4 + wid;        // 24576 tasks
  int b = task / 12, h = task - b * 12;
  int w = b & 63;
  const u16* base = qkv + (size_t)b * (NTOK * 1152);
  int c = lane & 15, g = lane >> 4;

  // ---- stage V transposed into LDS: vT[d][j], swizzled byte ^= (d&7)<<4 ----
  u16* vt = vT_lds[wid];
  {
    const u16* vbase = base + 2 * DIM + h * HD;
#pragma unroll
    for (int t = 0; t < 4; ++t) {
      int idx = t * 64 + lane;
      int j = idx >> 2, d0 = (idx & 3) * 8;
      int jr = j < NTOK ? j : NTOK - 1;
      u16x8 vv = *(const u16x8*)(vbase + (size_t)jr * 1152 + d0);
#pragma unroll
      for (int dd = 0; dd < 8; ++dd) {
        int d = d0 + dd;
        int byte = (d * 128 + j * 2) ^ ((d & 7) << 4);
        *(u16*)((char*)vt + byte) = (u16)vv[dd];
      }
    }
  }

  // ---- Q/K fragments straight from global (fragment-order along K=32) ----
  bf16x8 qa[4], kb[4];
#pragma unroll
  for (int mi = 0; mi < 4; ++mi) {
    int row = mi * 16 + c; if (row > NTOK - 1) row = NTOK - 1;
    qa[mi] = ld_bf8(base + (size_t)row * 1152 + h * HD + g * 8);
  }
#pragma unroll
  for (int ni = 0; ni < 4; ++ni) {
    int row = ni * 16 + c; if (row > NTOK - 1) row = NTOK - 1;
    kb[ni] = ld_bf8(base + (size_t)row * 1152 + DIM + h * HD + g * 8);
  }

  // ---- S = q @ k^T ----
  f32x4 s[4][4] = {};
#pragma unroll
  for (int mi = 0; mi < 4; ++mi)
#pragma unroll
    for (int ni = 0; ni < 4; ++ni)
      s[mi][ni] = __builtin_amdgcn_mfma_f32_16x16x32_bf16(qa[mi], kb[ni],
                                                          s[mi][ni], 0, 0, 0);

  // ---- scale + (bias+mask) from pre-swizzled table ----
  const float scale = 0.17677669529663687f;   // 32^-0.5
  const f32x4* rp = (const f32x4*)(rpbm + ((size_t)(h * 64 + w)) * 4096);
#pragma unroll
  for (int mi = 0; mi < 4; ++mi)
#pragma unroll
    for (int ni = 0; ni < 4; ++ni) {
      f32x4 rv = rp[(mi * 4 + ni) * 64 + lane];
#pragma unroll
      for (int r = 0; r < 4; ++r)
        s[mi][ni][r] = s[mi][ni][r] * scale + rv[r];
    }

  // ---- row softmax: row lives in one 16-lane group (per mi, r) ----
#pragma unroll
  for (int mi = 0; mi < 4; ++mi)
#pragma unroll
    for (int r = 0; r < 4; ++r) {
      float mx = fmaxf(fmaxf(s[mi][0][r], s[mi][1][r]),
                       fmaxf(s[mi][2][r], s[mi][3][r]));
      mx = fmaxf(mx, __shfl_xor(mx, 1));
      mx = fmaxf(mx, __shfl_xor(mx, 2));
      mx = fmaxf(mx, __shfl_xor(mx, 4));
      mx = fmaxf(mx, __shfl_xor(mx, 8));
      float sum = 0.f;
#pragma unroll
      for (int ni = 0; ni < 4; ++ni) {
        float p = __expf(s[mi][ni][r] - mx);
        s[mi][ni][r] = p;
        sum += p;
      }
      sum += __shfl_xor(sum, 1);
      sum += __shfl_xor(sum, 2);
      sum += __shfl_xor(sum, 4);
      sum += __shfl_xor(sum, 8);
      float inv = __builtin_amdgcn_rcpf(sum);
#pragma unroll
      for (int ni = 0; ni < 4; ++ni) s[mi][ni][r] *= inv;
    }

  // ---- P -> LDS as bf16 (swizzled) ----
  u16* pl = P_lds[wid];
#pragma unroll
  for (int mi = 0; mi < 4; ++mi)
#pragma unroll
    for (int ni = 0; ni < 4; ++ni) {
      int col = ni * 16 + c;
#pragma unroll
      for (int r = 0; r < 4; ++r) {
        int row = mi * 16 + g * 4 + r;
        int byte = (row * 128 + col * 2) ^ ((row & 7) << 4);
        *(u16*)((char*)pl + byte) = f2b(s[mi][ni][r]);
      }
    }
  asm volatile("s_waitcnt lgkmcnt(0)" ::: "memory");  // wave's LDS writes visible

  // ---- O = P @ V ----
  f32x4 o[4][2] = {};
#pragma unroll
  for (int ks = 0; ks < 2; ++ks) {
    bf16x8 vb[2];
#pragma unroll
    for (int n2 = 0; n2 < 2; ++n2) {
      int d = n2 * 16 + c;
      int byte = (d * 128 + ks * 64 + g * 16) ^ ((d & 7) << 4);
      vb[n2] = __builtin_bit_cast(bf16x8, *(const u16x8*)((const char*)vt + byte));
    }
#pragma unroll
    for (int mi = 0; mi < 4; ++mi) {
      int row = mi * 16 + c;
      int byte = (row * 128 + ks * 64 + g * 16) ^ ((row & 7) << 4);
      bf16x8 pa = __builtin_bit_cast(bf16x8, *(const u16x8*)((const char*)pl + byte));
#pragma unroll
      for (int n2 = 0; n2 < 2; ++n2)
        o[mi][n2] = __builtin_amdgcn_mfma_f32_16x16x32_bf16(pa, vb[n2],
                                                            o[mi][n2], 0, 0, 0);
    }
  }

  // ---- store O[b, row, h*32 + d] as bf16 ----
  u16* obase = attnout + (size_t)b * (NTOK * DIM) + h * HD;
#pragma unroll
  for (int mi = 0; mi < 4; ++mi)
#pragma unroll
    for (int r = 0; r < 4; ++r) {
      int row = mi * 16 + g * 4 + r;
      if (row < NTOK) {
#pragma unroll
        for (int n2 = 0; n2 < 2; ++n2)
          obase[(size_t)row * DIM + n2 * 16 + c] = f2b(o[mi][n2][r]);
      }
    }
}

// ---------------------------------------------------------------------------
extern "C" void kernel_launch(void* const* d_in, const int* in_sizes, int n_in,
                              void* d_out, int out_size, void* d_ws, size_t ws_size,
                              hipStream_t stream) {
  const float* x       = (const float*)d_in[0];
  const float* qkv_w   = (const float*)d_in[1];
  const float* qkv_b   = (const float*)d_in[2];
  const float* proj_w  = (const float*)d_in[3];
  const float* proj_b  = (const float*)d_in[4];
  const float* bias_tb = (const float*)d_in[5];
  const float* mask    = (const float*)d_in[6];
  const int*   rel_idx = (const int*)d_in[7];
  float* out = (float*)d_out;

  char* ws = (char*)d_ws;
  // workspace layout (bytes)
  u16*   xb      = (u16*)(ws + 0);                  //  77,070,336  x as bf16
  u16*   wqkvb   = (u16*)(ws + 77070336);           //     884,736  qkv_w bf16
  u16*   wprojb  = (u16*)(ws + 77955072);           //     294,912  proj_w bf16
  float* rpbm    = (float*)(ws + 78249984);         //  12,582,912  bias+mask
  u16*   qkv     = (u16*)(ws + 90832896);           // 231,211,008  qkv bf16
  u16*   attnout = (u16*)(ws + 322043904);          //  77,070,336  attn out bf16
  // total = 399,114,240 bytes

  // 1) casts
  k_cast<<<37632, 256, 0, stream>>>(x, xb, MROWS * DIM / 4);          // 9,633,792 quads
  k_cast<<<432, 256, 0, stream>>>(qkv_w, wqkvb, 3 * DIM * DIM / 4);   // 110,592
  k_cast<<<144, 256, 0, stream>>>(proj_w, wprojb, DIM * DIM / 4);     // 36,864

  // 2) fused bias+mask table (fragment-layout)
  k_rpbm<<<12288, 256, 0, stream>>>(bias_tb, mask, rel_idx, rpbm);

  // 3) QKV GEMM: [100352,384] x [1152,384]^T -> bf16 [100352,1152]
  k_gemm<1><<<7056, 256, 0, stream>>>(xb, wqkvb, qkv_b, qkv, DIM, 3 * DIM, 9, 882);

  // 4) window attention -> bf16 [100352,384]
  k_attn<<<6144, 256, 0, stream>>>(qkv, rpbm, attnout);

  // 5) proj GEMM: [100352,384] x [384,384]^T + bias -> f32 d_out
  k_gemm<0><<<2352, 256, 0, stream>>>(attnout, wprojb, proj_b, out, DIM, DIM, 3, 294);

  (void)in_sizes; (void)n_in; (void)out_size; (void)ws_size;
}

// Round 2
// 377.135 us; speedup vs baseline: 1.0124x; 1.0124x over previous
//
#include <hip/hip_runtime.h>
#include <hip/hip_bf16.h>
#include <cstdint>
#include <cstddef>

// Problem constants
#define NTOK 49
#define DIM 384
#define KDIM 384
#define HEADS 12
#define HD 32
#define BATCH 2048
#define MROWS (BATCH * NTOK)   // 100352 = 784 * 128

typedef unsigned short u16;
typedef __bf16 bf16x8 __attribute__((ext_vector_type(8)));
typedef unsigned short u16x8 __attribute__((ext_vector_type(8)));
typedef float f32x4 __attribute__((ext_vector_type(4)));

__device__ __forceinline__ u16 f2b(float f) {
  union { float f; unsigned u; } v; v.f = f;
  unsigned r = v.u + 0x7fffu + ((v.u >> 16) & 1u);   // RNE bf16
  return (u16)(r >> 16);
}

__device__ __forceinline__ bf16x8 ld_bf8(const u16* p) {
  u16x8 u = *(const u16x8*)p;
  return __builtin_bit_cast(bf16x8, u);
}

__device__ __forceinline__ void gload_lds16(const void* g, void* l) {
  __builtin_amdgcn_global_load_lds(
      (const __attribute__((address_space(1))) unsigned*)g,
      (__attribute__((address_space(3))) unsigned*)l, 16, 0, 0);
}

// ---------------- cast fp32 -> bf16 (weights only) ----------------
__global__ __launch_bounds__(256) void k_cast(const float* __restrict__ in,
                                              u16* __restrict__ out, int n4) {
  int i = blockIdx.x * 256 + threadIdx.x;
  if (i < n4) {
    float4 v = ((const float4*)in)[i];
    ushort4 o;
    o.x = f2b(v.x); o.y = f2b(v.y); o.z = f2b(v.z); o.w = f2b(v.w);
    ((ushort4*)out)[i] = o;
  }
}

// -------- fused rel-pos-bias + mask table, pre-swizzled to MFMA C-layout ----
__global__ __launch_bounds__(256) void k_rpbm(const float* __restrict__ bias_table,
                                              const float* __restrict__ mask,
                                              const int* __restrict__ rel_idx,
                                              float* __restrict__ out) {
  int idx = blockIdx.x * 256 + threadIdx.x;   // grid = 12*64*4096/256 = 12288
  int r  = idx & 3;
  int l  = (idx >> 2) & 63;
  int ni = (idx >> 8) & 3;
  int mi = (idx >> 10) & 3;
  int w  = (idx >> 12) & 63;
  int h  = idx >> 18;
  int row = mi * 16 + (l >> 4) * 4 + r;
  int col = ni * 16 + (l & 15);
  float v = -1e30f;
  if (row < NTOK && col < NTOK)
    v = bias_table[rel_idx[row * NTOK + col] * HEADS + h] +
        mask[(w * NTOK + row) * NTOK + col];
  out[idx] = v;
}

// ---------------- NT GEMM, 2-phase double-buffered ----------
// C[m,n] = sum_k A[m,k]*B[n,k] + bias[n]; K = 384 fixed.
// A_F32: A is f32 and cast-fused into staging (reg-stage, 1 iter ahead).
template <int OUT_BF16, int A_F32, int NCOLS, int NTN, int GD8>
__global__ __launch_bounds__(256) void k_gemm(const void* __restrict__ Av,
                                              const u16* __restrict__ B,
                                              const float* __restrict__ bias,
                                              void* __restrict__ Cv) {
  __shared__ u16 sh[16384];   // 32KB: 2 x (As 8KB + Bs 8KB); reused by epilogue
  int bid = blockIdx.x;
  int tile = (bid & 7) * GD8 + (bid >> 3);   // XCD-contiguous (grid % 8 == 0)
  int mt = tile / NTN, nt = tile - mt * NTN;
  long m0 = (long)mt * 128;
  int n0 = nt * 128;
  int tid = threadIdx.x;
  int lane = tid & 63, wid = tid >> 6;
  int wr = (wid >> 1) * 64, wc = (wid & 1) * 64;
  int c = lane & 15, g = lane >> 4;

  // gload_lds staging coords (LDS dest is wave-uniform base + lane*16: offset
  // (srow*32+scol)*2 == wid*1024 + lane*16 -> contiguous in lane order)
  int srow = wid * 16 + (lane >> 2);
  int scol = (lane & 3) * 8;
  const u16* gB = B + (long)(n0 + srow) * KDIM + scol;

  const u16* gA16 = nullptr;
  const float* gAf = nullptr;
  float4 areg[4];
  int arow = tid >> 3;            // 0..31  (8 lanes cover one 128B f32 row-chunk)
  int acol = (tid & 7) * 4;       // 0..28
  if (A_F32) {
    gAf = (const float*)Av + (m0 + arow) * KDIM + acol;
#pragma unroll
    for (int rp = 0; rp < 4; ++rp)
      areg[rp] = *(const float4*)(gAf + rp * 32 * KDIM);
  } else {
    gA16 = (const u16*)Av + (m0 + srow) * (long)KDIM + scol;
  }

  f32x4 acc[4][4] = {};

  auto STAGE = [&](int buf, int ktS) {
    u16* As = sh + buf * 8192;
    u16* Bs = As + 4096;
    if (A_F32) {
      // write current areg (cols [ktS, ktS+32)) as bf16, then prefetch next
#pragma unroll
      for (int rp = 0; rp < 4; ++rp) {
        float4 v = areg[rp];
        ushort4 o; o.x = f2b(v.x); o.y = f2b(v.y); o.z = f2b(v.z); o.w = f2b(v.w);
        *(ushort4*)&As[(rp * 32 + arow) * 32 + acol] = o;
      }
      if (ktS + 32 < KDIM) {
#pragma unroll
        for (int rp = 0; rp < 4; ++rp)
          areg[rp] = *(const float4*)(gAf + rp * 32 * KDIM + (ktS + 32));
      }
    } else {
      gload_lds16(gA16 + ktS, &((u16*)As)[srow * 32 + scol]);
      gload_lds16(gA16 + ktS + 64L * KDIM, &((u16*)As)[(srow + 64) * 32 + scol]);
    }
    gload_lds16(gB + ktS, &Bs[srow * 32 + scol]);
    gload_lds16(gB + ktS + 64L * KDIM, &Bs[(srow + 64) * 32 + scol]);
  };

  STAGE(0, 0);
  __syncthreads();              // full drain (vmcnt0+lgkm0) before first use
  int cur = 0;
  for (int kt = 0; kt < KDIM; kt += 32) {
    if (kt + 32 < KDIM) STAGE(cur ^ 1, kt + 32);   // overlaps with MFMA below
    const u16* As = sh + cur * 8192;
    const u16* Bs = As + 4096;
    bf16x8 af[4], bfr[4];
#pragma unroll
    for (int i = 0; i < 4; ++i) {
      af[i]  = ld_bf8(&As[(wr + i * 16 + c) * 32 + g * 8]);
      bfr[i] = ld_bf8(&Bs[(wc + i * 16 + c) * 32 + g * 8]);
    }
#pragma unroll
    for (int mi = 0; mi < 4; ++mi)
#pragma unroll
      for (int ni = 0; ni < 4; ++ni)
        acc[mi][ni] = __builtin_amdgcn_mfma_f32_16x16x32_bf16(
            af[mi], bfr[ni], acc[mi][ni], 0, 0, 0);
    __syncthreads();            // drains this iter's staging; all waves done reading
    cur ^= 1;
  }

  // ---- epilogue: LDS transit -> coalesced 16B stores ----
  if (OUT_BF16) {
    u16* C = (u16*)Cv;
#pragma unroll
    for (int mi = 0; mi < 4; ++mi)
#pragma unroll
      for (int ni = 0; ni < 4; ++ni) {
        int col = wc + ni * 16 + c;
        float bv = bias[n0 + col];
#pragma unroll
        for (int r = 0; r < 4; ++r) {
          int row = wr + mi * 16 + g * 4 + r;
          sh[row * 128 + col] = f2b(acc[mi][ni][r] + bv);
        }
      }
    __syncthreads();
#pragma unroll
    for (int rep = 0; rep < 8; ++rep) {
      int idx = rep * 2048 + tid * 8;      // u16 units; 16 rows per rep
      int row = idx >> 7, col = idx & 127;
      *(u16x8*)(C + (m0 + row) * NCOLS + n0 + col) = *(const u16x8*)&sh[idx];
    }
  } else {
    float* C = (float*)Cv;
    float* shf = (float*)sh;               // 8192 f32 = 32KB = 64 rows x 128 cols
#pragma unroll
    for (int chunk = 0; chunk < 2; ++chunk) {
      __syncthreads();
      if ((wr >> 6) == chunk) {
#pragma unroll
        for (int mi = 0; mi < 4; ++mi)
#pragma unroll
          for (int ni = 0; ni < 4; ++ni) {
            int col = wc + ni * 16 + c;
            float bv = bias[n0 + col];
#pragma unroll
            for (int r = 0; r < 4; ++r) {
              int lrow = mi * 16 + g * 4 + r;   // rows within this 64-row chunk
              shf[lrow * 128 + col] = acc[mi][ni][r] + bv;
            }
          }
      }
      __syncthreads();
#pragma unroll
      for (int rep = 0; rep < 8; ++rep) {
        int idx = rep * 1024 + tid * 4;    // f32 units; 8 rows per rep
        int row = idx >> 7, col = idx & 127;
        *(float4*)(C + (m0 + chunk * 64 + row) * NCOLS + n0 + col) =
            *(const float4*)&shf[idx];
      }
    }
  }
}

// ---------------- fused window attention: one wave per (b, h) ----------------
__global__ __launch_bounds__(256) void k_attn(const u16* __restrict__ qkv,
                                              const float* __restrict__ rpbm,
                                              u16* __restrict__ attnout) {
  __shared__ u16 P_lds[4][64 * 64];
  __shared__ u16 vT_lds[4][32 * 64];
  int lane = threadIdx.x & 63, wid = threadIdx.x >> 6;
  // w-major remap: 96 consecutive blocks share one window's rpbm tables (L2),
  // the 4 waves of a block are 4 heads of the same b (qkv line sharing).
  int blk = blockIdx.x;                  // 0..6143
  int w = blk / 96;
  int rr = blk - w * 96;
  int j = rr / 3;
  int hb = rr - j * 3;
  int b = j * 64 + w;
  int h = hb * 4 + wid;
  const u16* base = qkv + (size_t)b * (NTOK * 1152);
  int c = lane & 15, g = lane >> 4;

  // ---- stage V transposed into LDS: vT[d][j], swizzled byte ^= (d&7)<<4 ----
  u16* vt = vT_lds[wid];
  {
    const u16* vbase = base + 2 * DIM + h * HD;
#pragma unroll
    for (int t = 0; t < 4; ++t) {
      int idx = t * 64 + lane;
      int jj = idx >> 2, d0 = (idx & 3) * 8;
      int jr = jj < NTOK ? jj : NTOK - 1;
      u16x8 vv = *(const u16x8*)(vbase + (size_t)jr * 1152 + d0);
#pragma unroll
      for (int dd = 0; dd < 8; ++dd) {
        int d = d0 + dd;
        int byte = (d * 128 + jj * 2) ^ ((d & 7) << 4);
        *(u16*)((char*)vt + byte) = (u16)vv[dd];
      }
    }
  }

  // ---- Q/K fragments straight from global (fragment-order along K=32) ----
  bf16x8 qa[4], kb[4];
#pragma unroll
  for (int mi = 0; mi < 4; ++mi) {
    int row = mi * 16 + c; if (row > NTOK - 1) row = NTOK - 1;
    qa[mi] = ld_bf8(base + (size_t)row * 1152 + h * HD + g * 8);
  }
#pragma unroll
  for (int ni = 0; ni < 4; ++ni) {
    int row = ni * 16 + c; if (row > NTOK - 1) row = NTOK - 1;
    kb[ni] = ld_bf8(base + (size_t)row * 1152 + DIM + h * HD + g * 8);
  }

  // ---- S = q @ k^T ----
  f32x4 s[4][4] = {};
#pragma unroll
  for (int mi = 0; mi < 4; ++mi)
#pragma unroll
    for (int ni = 0; ni < 4; ++ni)
      s[mi][ni] = __builtin_amdgcn_mfma_f32_16x16x32_bf16(qa[mi], kb[ni],
                                                          s[mi][ni], 0, 0, 0);

  // ---- scale + (bias+mask) from pre-swizzled table ----
  const float scale = 0.17677669529663687f;   // 32^-0.5
  const f32x4* rp = (const f32x4*)(rpbm + ((size_t)(h * 64 + w)) * 4096);
#pragma unroll
  for (int mi = 0; mi < 4; ++mi)
#pragma unroll
    for (int ni = 0; ni < 4; ++ni) {
      f32x4 rv = rp[(mi * 4 + ni) * 64 + lane];
#pragma unroll
      for (int r = 0; r < 4; ++r)
        s[mi][ni][r] = s[mi][ni][r] * scale + rv[r];
    }

  // ---- row softmax: row lives in one 16-lane group (per mi, r) ----
#pragma unroll
  for (int mi = 0; mi < 4; ++mi)
#pragma unroll
    for (int r = 0; r < 4; ++r) {
      float mx = fmaxf(fmaxf(s[mi][0][r], s[mi][1][r]),
                       fmaxf(s[mi][2][r], s[mi][3][r]));
      mx = fmaxf(mx, __shfl_xor(mx, 1));
      mx = fmaxf(mx, __shfl_xor(mx, 2));
      mx = fmaxf(mx, __shfl_xor(mx, 4));
      mx = fmaxf(mx, __shfl_xor(mx, 8));
      float sum = 0.f;
#pragma unroll
      for (int ni = 0; ni < 4; ++ni) {
        float p = __expf(s[mi][ni][r] - mx);
        s[mi][ni][r] = p;
        sum += p;
      }
      sum += __shfl_xor(sum, 1);
      sum += __shfl_xor(sum, 2);
      sum += __shfl_xor(sum, 4);
      sum += __shfl_xor(sum, 8);
      float inv = __builtin_amdgcn_rcpf(sum);
#pragma unroll
      for (int ni = 0; ni < 4; ++ni) s[mi][ni][r] *= inv;
    }

  // ---- P -> LDS as bf16 (swizzled) ----
  u16* pl = P_lds[wid];
#pragma unroll
  for (int mi = 0; mi < 4; ++mi)
#pragma unroll
    for (int ni = 0; ni < 4; ++ni) {
      int col = ni * 16 + c;
#pragma unroll
      for (int r = 0; r < 4; ++r) {
        int row = mi * 16 + g * 4 + r;
        int byte = (row * 128 + col * 2) ^ ((row & 7) << 4);
        *(u16*)((char*)pl + byte) = f2b(s[mi][ni][r]);
      }
    }
  asm volatile("s_waitcnt lgkmcnt(0)" ::: "memory");  // wave's LDS writes visible

  // ---- O = P @ V ----
  f32x4 o[4][2] = {};
#pragma unroll
  for (int ks = 0; ks < 2; ++ks) {
    bf16x8 vb[2];
#pragma unroll
    for (int n2 = 0; n2 < 2; ++n2) {
      int d = n2 * 16 + c;
      int byte = (d * 128 + ks * 64 + g * 16) ^ ((d & 7) << 4);
      vb[n2] = __builtin_bit_cast(bf16x8, *(const u16x8*)((const char*)vt + byte));
    }
#pragma unroll
    for (int mi = 0; mi < 4; ++mi) {
      int row = mi * 16 + c;
      int byte = (row * 128 + ks * 64 + g * 16) ^ ((row & 7) << 4);
      bf16x8 pa = __builtin_bit_cast(bf16x8, *(const u16x8*)((const char*)pl + byte));
#pragma unroll
      for (int n2 = 0; n2 < 2; ++n2)
        o[mi][n2] = __builtin_amdgcn_mfma_f32_16x16x32_bf16(pa, vb[n2],
                                                            o[mi][n2], 0, 0, 0);
    }
  }

  // ---- store O[b, row, h*32 + d] as bf16 ----
  u16* obase = attnout + (size_t)b * (NTOK * DIM) + h * HD;
#pragma unroll
  for (int mi = 0; mi < 4; ++mi)
#pragma unroll
    for (int r = 0; r < 4; ++r) {
      int row = mi * 16 + g * 4 + r;
      if (row < NTOK) {
#pragma unroll
        for (int n2 = 0; n2 < 2; ++n2)
          obase[(size_t)row * DIM + n2 * 16 + c] = f2b(o[mi][n2][r]);
      }
    }
}

// ---------------------------------------------------------------------------
extern "C" void kernel_launch(void* const* d_in, const int* in_sizes, int n_in,
                              void* d_out, int out_size, void* d_ws, size_t ws_size,
                              hipStream_t stream) {
  const float* x       = (const float*)d_in[0];
  const float* qkv_w   = (const float*)d_in[1];
  const float* qkv_b   = (const float*)d_in[2];
  const float* proj_w  = (const float*)d_in[3];
  const float* proj_b  = (const float*)d_in[4];
  const float* bias_tb = (const float*)d_in[5];
  const float* mask    = (const float*)d_in[6];
  const int*   rel_idx = (const int*)d_in[7];
  float* out = (float*)d_out;

  char* ws = (char*)d_ws;
  // workspace layout (bytes)
  u16*   wqkvb   = (u16*)(ws + 0);                  //     884,736  qkv_w bf16
  u16*   wprojb  = (u16*)(ws + 884736);             //     294,912  proj_w bf16
  float* rpbm    = (float*)(ws + 1179648);          //  12,582,912  bias+mask
  u16*   qkv     = (u16*)(ws + 13762560);           // 231,211,008  qkv bf16
  u16*   attnout = (u16*)(ws + 244973568);          //  77,070,336  attn out bf16
  // total = 322,043,904 bytes

  // 1) weight casts (x cast is fused into the QKV GEMM staging)
  k_cast<<<432, 256, 0, stream>>>(qkv_w, wqkvb, 3 * DIM * DIM / 4);
  k_cast<<<144, 256, 0, stream>>>(proj_w, wprojb, DIM * DIM / 4);

  // 2) fused bias+mask table (fragment-layout)
  k_rpbm<<<12288, 256, 0, stream>>>(bias_tb, mask, rel_idx, rpbm);

  // 3) QKV GEMM: f32 x [100352,384] (cast-fused) x [1152,384]^T -> bf16
  k_gemm<1, 1, 1152, 9, 882><<<7056, 256, 0, stream>>>(
      (const void*)x, wqkvb, qkv_b, (void*)qkv);

  // 4) window attention -> bf16 [100352,384]
  k_attn<<<6144, 256, 0, stream>>>(qkv, rpbm, attnout);

  // 5) proj GEMM: [100352,384] x [384,384]^T + bias -> f32 d_out
  k_gemm<0, 0, 384, 3, 294><<<2352, 256, 0, stream>>>(
      (const void*)attnout, wprojb, proj_b, (void*)out);

  (void)in_sizes; (void)n_in; (void)out_size; (void)ws_size;
}

// Round 3
// 373.057 us; speedup vs baseline: 1.0235x; 1.0109x over previous
//
#include <hip/hip_runtime.h>
#include <hip/hip_bf16.h>
#include <cstdint>
#include <cstddef>

// Problem constants
#define NTOK 49
#define DIM 384
#define KDIM 384
#define HEADS 12
#define HD 32
#define BATCH 2048
#define MROWS (BATCH * NTOK)   // 100352 = 784 * 128

typedef unsigned short u16;
typedef __bf16 bf16x8 __attribute__((ext_vector_type(8)));
typedef unsigned short u16x8 __attribute__((ext_vector_type(8)));
typedef float f32x4 __attribute__((ext_vector_type(4)));

__device__ __forceinline__ u16 f2b(float f) {
  union { float f; unsigned u; } v; v.f = f;
  unsigned r = v.u + 0x7fffu + ((v.u >> 16) & 1u);   // RNE bf16
  return (u16)(r >> 16);
}

__device__ __forceinline__ bf16x8 ld_bf8(const u16* p) {
  u16x8 u = *(const u16x8*)p;
  return __builtin_bit_cast(bf16x8, u);
}

__device__ __forceinline__ void gload_lds16(const void* g, void* l) {
  __builtin_amdgcn_global_load_lds(
      (const __attribute__((address_space(1))) unsigned*)g,
      (__attribute__((address_space(3))) unsigned*)l, 16, 0, 0);
}

// ---------------- prep: x/w casts + fused bias+mask table, one launch -------
// blocks [0,37632): cast x (9,633,792 float4 quads)
// blocks [37632,38064): cast qkv_w (110,592 quads)
// blocks [38064,38208): cast proj_w (36,864 quads)
// blocks [38208,50496): rpbm table (12288 blocks)
__global__ __launch_bounds__(256) void k_prep(const float* __restrict__ x,
                                              u16* __restrict__ xb,
                                              const float* __restrict__ qkv_w,
                                              u16* __restrict__ wqkvb,
                                              const float* __restrict__ proj_w,
                                              u16* __restrict__ wprojb,
                                              const float* __restrict__ bias_table,
                                              const float* __restrict__ mask,
                                              const int* __restrict__ rel_idx,
                                              float* __restrict__ rpbm) {
  int blk = blockIdx.x;
  if (blk < 38208) {
    const float* in;
    u16* out;
    int i;
    if (blk < 37632) {
      in = x; out = xb; i = blk * 256 + threadIdx.x;
    } else if (blk < 38064) {
      in = qkv_w; out = wqkvb; i = (blk - 37632) * 256 + threadIdx.x;
    } else {
      in = proj_w; out = wprojb; i = (blk - 38064) * 256 + threadIdx.x;
    }
    float4 v = ((const float4*)in)[i];
    ushort4 o;
    o.x = f2b(v.x); o.y = f2b(v.y); o.z = f2b(v.z); o.w = f2b(v.w);
    ((ushort4*)out)[i] = o;
  } else {
    int idx = (blk - 38208) * 256 + threadIdx.x;   // 12*64*4096 entries
    int r  = idx & 3;
    int l  = (idx >> 2) & 63;
    int ni = (idx >> 8) & 3;
    int mi = (idx >> 10) & 3;
    int w  = (idx >> 12) & 63;
    int h  = idx >> 18;
    int row = mi * 16 + (l >> 4) * 4 + r;
    int col = ni * 16 + (l & 15);
    float v = -1e30f;
    if (row < NTOK && col < NTOK)
      v = bias_table[rel_idx[row * NTOK + col] * HEADS + h] +
          mask[(w * NTOK + row) * NTOK + col];
    rpbm[idx] = v;
  }
}

// ---------------- NT GEMM, 2-phase double-buffered, gload_lds staging -------
// C[m,n] = sum_k A[m,k]*B[n,k] + bias[n]; K = 384 fixed.
// A [M,K] bf16 row-major, B [N,K] bf16 row-major.
template <int OUT_BF16, int NCOLS, int NTN, int GD8>
__global__ __launch_bounds__(256) void k_gemm(const u16* __restrict__ A,
                                              const u16* __restrict__ B,
                                              const float* __restrict__ bias,
                                              void* __restrict__ Cv) {
  __shared__ u16 sh[16384];   // 32KB: 2 x (As 8KB + Bs 8KB); reused by epilogue
  int bid = blockIdx.x;
  int tile = (bid & 7) * GD8 + (bid >> 3);   // XCD-contiguous (grid % 8 == 0)
  int mt = tile / NTN, nt = tile - mt * NTN;
  long m0 = (long)mt * 128;
  int n0 = nt * 128;
  int tid = threadIdx.x;
  int lane = tid & 63, wid = tid >> 6;
  int wr = (wid >> 1) * 64, wc = (wid & 1) * 64;
  int c = lane & 15, g = lane >> 4;

  // gload_lds staging coords: LDS byte offset = wid*1024 + lane*16 ->
  // wave-uniform base + lane*16 (required layout for global_load_lds)
  int srow = wid * 16 + (lane >> 2);
  int scol = (lane & 3) * 8;
  const u16* gA = A + (m0 + srow) * (long)KDIM + scol;
  const u16* gB = B + (long)(n0 + srow) * KDIM + scol;

  f32x4 acc[4][4] = {};

  auto STAGE = [&](int buf, int ktS) {
    u16* As = sh + buf * 8192;
    u16* Bs = As + 4096;
    gload_lds16(gA + ktS, &As[srow * 32 + scol]);
    gload_lds16(gA + ktS + 64L * KDIM, &As[(srow + 64) * 32 + scol]);
    gload_lds16(gB + ktS, &Bs[srow * 32 + scol]);
    gload_lds16(gB + ktS + 64L * KDIM, &Bs[(srow + 64) * 32 + scol]);
  };

  STAGE(0, 0);
  __syncthreads();              // full drain (vmcnt0+lgkm0) before first use
  int cur = 0;
  for (int kt = 0; kt < KDIM; kt += 32) {
    if (kt + 32 < KDIM) STAGE(cur ^ 1, kt + 32);   // in flight across MFMA
    const u16* As = sh + cur * 8192;
    const u16* Bs = As + 4096;
    bf16x8 af[4], bfr[4];
#pragma unroll
    for (int i = 0; i < 4; ++i) {
      af[i]  = ld_bf8(&As[(wr + i * 16 + c) * 32 + g * 8]);
      bfr[i] = ld_bf8(&Bs[(wc + i * 16 + c) * 32 + g * 8]);
    }
#pragma unroll
    for (int mi = 0; mi < 4; ++mi)
#pragma unroll
      for (int ni = 0; ni < 4; ++ni)
        acc[mi][ni] = __builtin_amdgcn_mfma_f32_16x16x32_bf16(
            af[mi], bfr[ni], acc[mi][ni], 0, 0, 0);
    __syncthreads();            // drains this iter's staging loads
    cur ^= 1;
  }

  // ---- epilogue: LDS transit -> coalesced 16B stores ----
  if (OUT_BF16) {
    u16* C = (u16*)Cv;
#pragma unroll
    for (int mi = 0; mi < 4; ++mi)
#pragma unroll
      for (int ni = 0; ni < 4; ++ni) {
        int col = wc + ni * 16 + c;
        float bv = bias[n0 + col];
#pragma unroll
        for (int r = 0; r < 4; ++r) {
          int row = wr + mi * 16 + g * 4 + r;
          sh[row * 128 + col] = f2b(acc[mi][ni][r] + bv);
        }
      }
    __syncthreads();
#pragma unroll
    for (int rep = 0; rep < 8; ++rep) {
      int idx = rep * 2048 + tid * 8;      // u16 units; 16 rows per rep
      int row = idx >> 7, col = idx & 127;
      *(u16x8*)(C + (m0 + row) * NCOLS + n0 + col) = *(const u16x8*)&sh[idx];
    }
  } else {
    float* C = (float*)Cv;
    float* shf = (float*)sh;               // 8192 f32 = 32KB = 64 rows x 128 cols
#pragma unroll
    for (int chunk = 0; chunk < 2; ++chunk) {
      __syncthreads();
      if ((wr >> 6) == chunk) {
#pragma unroll
        for (int mi = 0; mi < 4; ++mi)
#pragma unroll
          for (int ni = 0; ni < 4; ++ni) {
            int col = wc + ni * 16 + c;
            float bv = bias[n0 + col];
#pragma unroll
            for (int r = 0; r < 4; ++r) {
              int lrow = mi * 16 + g * 4 + r;
              shf[lrow * 128 + col] = acc[mi][ni][r] + bv;
            }
          }
      }
      __syncthreads();
#pragma unroll
      for (int rep = 0; rep < 8; ++rep) {
        int idx = rep * 1024 + tid * 4;    // f32 units; 8 rows per rep
        int row = idx >> 7, col = idx & 127;
        *(float4*)(C + (m0 + chunk * 64 + row) * NCOLS + n0 + col) =
            *(const float4*)&shf[idx];
      }
    }
  }
}

// ---------------- fused window attention: one wave per (b, h) ----------------
__global__ __launch_bounds__(256) void k_attn(const u16* __restrict__ qkv,
                                              const float* __restrict__ rpbm,
                                              u16* __restrict__ attnout) {
  __shared__ u16 P_lds[4][64 * 64];
  __shared__ u16 vT_lds[4][32 * 64];
  int lane = threadIdx.x & 63, wid = threadIdx.x >> 6;
  // w-major remap: 96 consecutive blocks share one window's rpbm tables (L2),
  // the 4 waves of a block are 4 heads of the same b (qkv line sharing).
  int blk = blockIdx.x;                  // 0..6143
  int w = blk / 96;
  int rr = blk - w * 96;
  int j = rr / 3;
  int hb = rr - j * 3;
  int b = j * 64 + w;
  int h = hb * 4 + wid;
  const u16* base = qkv + (size_t)b * (NTOK * 1152);
  int c = lane & 15, g = lane >> 4;

  // ---- stage V transposed into LDS: vT[d][j], swizzled byte ^= (d&7)<<4 ----
  u16* vt = vT_lds[wid];
  {
    const u16* vbase = base + 2 * DIM + h * HD;
#pragma unroll
    for (int t = 0; t < 4; ++t) {
      int idx = t * 64 + lane;
      int jj = idx >> 2, d0 = (idx & 3) * 8;
      int jr = jj < NTOK ? jj : NTOK - 1;
      u16x8 vv = *(const u16x8*)(vbase + (size_t)jr * 1152 + d0);
#pragma unroll
      for (int dd = 0; dd < 8; ++dd) {
        int d = d0 + dd;
        int byte = (d * 128 + jj * 2) ^ ((d & 7) << 4);
        *(u16*)((char*)vt + byte) = (u16)vv[dd];
      }
    }
  }

  // ---- Q/K fragments straight from global (fragment-order along K=32) ----
  bf16x8 qa[4], kb[4];
#pragma unroll
  for (int mi = 0; mi < 4; ++mi) {
    int row = mi * 16 + c; if (row > NTOK - 1) row = NTOK - 1;
    qa[mi] = ld_bf8(base + (size_t)row * 1152 + h * HD + g * 8);
  }
#pragma unroll
  for (int ni = 0; ni < 4; ++ni) {
    int row = ni * 16 + c; if (row > NTOK - 1) row = NTOK - 1;
    kb[ni] = ld_bf8(base + (size_t)row * 1152 + DIM + h * HD + g * 8);
  }

  // ---- S = q @ k^T ----
  f32x4 s[4][4] = {};
#pragma unroll
  for (int mi = 0; mi < 4; ++mi)
#pragma unroll
    for (int ni = 0; ni < 4; ++ni)
      s[mi][ni] = __builtin_amdgcn_mfma_f32_16x16x32_bf16(qa[mi], kb[ni],
                                                          s[mi][ni], 0, 0, 0);

  // ---- scale + (bias+mask) from pre-swizzled table ----
  const float scale = 0.17677669529663687f;   // 32^-0.5
  const f32x4* rp = (const f32x4*)(rpbm + ((size_t)(h * 64 + w)) * 4096);
#pragma unroll
  for (int mi = 0; mi < 4; ++mi)
#pragma unroll
    for (int ni = 0; ni < 4; ++ni) {
      f32x4 rv = rp[(mi * 4 + ni) * 64 + lane];
#pragma unroll
      for (int r = 0; r < 4; ++r)
        s[mi][ni][r] = s[mi][ni][r] * scale + rv[r];
    }

  // ---- row softmax: row lives in one 16-lane group (per mi, r) ----
#pragma unroll
  for (int mi = 0; mi < 4; ++mi)
#pragma unroll
    for (int r = 0; r < 4; ++r) {
      float mx = fmaxf(fmaxf(s[mi][0][r], s[mi][1][r]),
                       fmaxf(s[mi][2][r], s[mi][3][r]));
      mx = fmaxf(mx, __shfl_xor(mx, 1));
      mx = fmaxf(mx, __shfl_xor(mx, 2));
      mx = fmaxf(mx, __shfl_xor(mx, 4));
      mx = fmaxf(mx, __shfl_xor(mx, 8));
      float sum = 0.f;
#pragma unroll
      for (int ni = 0; ni < 4; ++ni) {
        float p = __expf(s[mi][ni][r] - mx);
        s[mi][ni][r] = p;
        sum += p;
      }
      sum += __shfl_xor(sum, 1);
      sum += __shfl_xor(sum, 2);
      sum += __shfl_xor(sum, 4);
      sum += __shfl_xor(sum, 8);
      float inv = __builtin_amdgcn_rcpf(sum);
#pragma unroll
      for (int ni = 0; ni < 4; ++ni) s[mi][ni][r] *= inv;
    }

  // ---- P -> LDS as bf16 (swizzled) ----
  u16* pl = P_lds[wid];
#pragma unroll
  for (int mi = 0; mi < 4; ++mi)
#pragma unroll
    for (int ni = 0; ni < 4; ++ni) {
      int col = ni * 16 + c;
#pragma unroll
      for (int r = 0; r < 4; ++r) {
        int row = mi * 16 + g * 4 + r;
        int byte = (row * 128 + col * 2) ^ ((row & 7) << 4);
        *(u16*)((char*)pl + byte) = f2b(s[mi][ni][r]);
      }
    }
  asm volatile("s_waitcnt lgkmcnt(0)" ::: "memory");  // wave's LDS writes visible

  // ---- O = P @ V ----
  f32x4 o[4][2] = {};
#pragma unroll
  for (int ks = 0; ks < 2; ++ks) {
    bf16x8 vb[2];
#pragma unroll
    for (int n2 = 0; n2 < 2; ++n2) {
      int d = n2 * 16 + c;
      int byte = (d * 128 + ks * 64 + g * 16) ^ ((d & 7) << 4);
      vb[n2] = __builtin_bit_cast(bf16x8, *(const u16x8*)((const char*)vt + byte));
    }
#pragma unroll
    for (int mi = 0; mi < 4; ++mi) {
      int row = mi * 16 + c;
      int byte = (row * 128 + ks * 64 + g * 16) ^ ((row & 7) << 4);
      bf16x8 pa = __builtin_bit_cast(bf16x8, *(const u16x8*)((const char*)pl + byte));
#pragma unroll
      for (int n2 = 0; n2 < 2; ++n2)
        o[mi][n2] = __builtin_amdgcn_mfma_f32_16x16x32_bf16(pa, vb[n2],
                                                            o[mi][n2], 0, 0, 0);
    }
  }

  // ---- store O[b, row, h*32 + d] as bf16 ----
  u16* obase = attnout + (size_t)b * (NTOK * DIM) + h * HD;
#pragma unroll
  for (int mi = 0; mi < 4; ++mi)
#pragma unroll
    for (int r = 0; r < 4; ++r) {
      int row = mi * 16 + g * 4 + r;
      if (row < NTOK) {
#pragma unroll
        for (int n2 = 0; n2 < 2; ++n2)
          obase[(size_t)row * DIM + n2 * 16 + c] = f2b(o[mi][n2][r]);
      }
    }
}

// ---------------------------------------------------------------------------
extern "C" void kernel_launch(void* const* d_in, const int* in_sizes, int n_in,
                              void* d_out, int out_size, void* d_ws, size_t ws_size,
                              hipStream_t stream) {
  const float* x       = (const float*)d_in[0];
  const float* qkv_w   = (const float*)d_in[1];
  const float* qkv_b   = (const float*)d_in[2];
  const float* proj_w  = (const float*)d_in[3];
  const float* proj_b  = (const float*)d_in[4];
  const float* bias_tb = (const float*)d_in[5];
  const float* mask    = (const float*)d_in[6];
  const int*   rel_idx = (const int*)d_in[7];
  float* out = (float*)d_out;

  char* ws = (char*)d_ws;
  // workspace layout (bytes)
  u16*   xb      = (u16*)(ws + 0);                  //  77,070,336  x as bf16
  u16*   wqkvb   = (u16*)(ws + 77070336);           //     884,736  qkv_w bf16
  u16*   wprojb  = (u16*)(ws + 77955072);           //     294,912  proj_w bf16
  float* rpbm    = (float*)(ws + 78249984);         //  12,582,912  bias+mask
  u16*   qkv     = (u16*)(ws + 90832896);           // 231,211,008  qkv bf16
  u16*   attnout = (u16*)(ws + 322043904);          //  77,070,336  attn out bf16
  // total = 399,114,240 bytes

  // 1) prep: all casts + fused bias+mask table in one launch
  k_prep<<<50496, 256, 0, stream>>>(x, xb, qkv_w, wqkvb, proj_w, wprojb,
                                    bias_tb, mask, rel_idx, rpbm);

  // 2) QKV GEMM: [100352,384] x [1152,384]^T -> bf16 [100352,1152]
  k_gemm<1, 1152, 9, 882><<<7056, 256, 0, stream>>>(xb, wqkvb, qkv_b, (void*)qkv);

  // 3) window attention -> bf16 [100352,384]
  k_attn<<<6144, 256, 0, stream>>>(qkv, rpbm, attnout);

  // 4) proj GEMM: [100352,384] x [384,384]^T + bias -> f32 d_out
  k_gemm<0, 384, 3, 294><<<2352, 256, 0, stream>>>(attnout, wprojb, proj_b,
                                                   (void*)out);

  (void)in_sizes; (void)n_in; (void)out_size; (void)ws_size;
}